// Round 7
// baseline (87.300 us; speedup 1.0000x reference)
//
#include <hip/hip_runtime.h>
#include <hip/hip_bf16.h>

typedef __attribute__((ext_vector_type(8))) short short8;
typedef __attribute__((ext_vector_type(4))) float f32x4;
typedef __attribute__((ext_vector_type(4))) unsigned int u32x4;
typedef __attribute__((ext_vector_type(2))) unsigned int u32x2;

#define DFEAT 128
#define LDW 136   // Wt row stride in shorts

__device__ __forceinline__ unsigned short f2bf(float f) {
    unsigned int u = __float_as_uint(f);
    u += 0x7FFFu + ((u >> 16) & 1u);   // round-nearest-even
    return (unsigned short)(u >> 16);
}
// packed f32x2 -> bf16x2, RNE (gfx950 v_cvt_pk_bf16_f32)
__device__ __forceinline__ unsigned int cvt2(float lo, float hi) {
    unsigned int r;
    asm("v_cvt_pk_bf16_f32 %0, %1, %2" : "=v"(r) : "v"(lo), "v"(hi));
    return r;
}
__device__ __forceinline__ float bf2f(unsigned int bits) {
    return __uint_as_float(bits << 16);
}

__device__ __forceinline__ void load_strip(float4 (&buf)[8], const float* __restrict__ z,
                                           int ss, int nN, int l15, int kg) {
    int row = ss * 16 + l15;
    const float* zr = z + (size_t)(row < nN ? row : nN - 1) * DFEAT + kg * 8;
#pragma unroll
    for (int kk = 0; kk < 4; ++kk) {
        buf[2 * kk]     = *(const float4*)(zr + kk * 32);
        buf[2 * kk + 1] = *(const float4*)(zr + kk * 32 + 4);
    }
}

// Phase 1: A[n][:] = zi[n] @ W1[0:128][:] + b1 (table 0);  B analogous (table 1).
// One wave per 16x128 strip; swapped MFMA operands -> packed 8B stores.
// TWO named fp32 strip buffers (c0/c1) + manual 2x unroll = real 2-deep
// prefetch pipeline; sched_barrier(0) after each prefetch-issue stops the
// compiler from sinking the loads to their use (round-6: VGPR=52 proved it did).
__global__ __launch_bounds__(256) void node_gemm(
    const float* __restrict__ zi, const float* __restrict__ zj,
    const float* __restrict__ W1, const float* __restrict__ b1,
    unsigned short* __restrict__ Aout, unsigned short* __restrict__ Bout,
    int nN)
{
    __shared__ unsigned short Wt[128][LDW];   // Wt[col][k] bf16
    __shared__ float bias_lds[128];
    const int table = blockIdx.y;
    const float* __restrict__ z = table ? zj : zi;
    unsigned short* __restrict__ outp = table ? Bout : Aout;

    for (int idx = threadIdx.x; idx < 128 * 128; idx += 256) {
        int c = idx & 127, k = idx >> 7;
        Wt[c][k] = f2bf(W1[(size_t)(table * 128 + k) * DFEAT + c]);
    }
    if (threadIdx.x < 128) bias_lds[threadIdx.x] = table ? 0.f : b1[threadIdx.x];
    __syncthreads();

    const int lane = threadIdx.x & 63;
    const int l15  = lane & 15;
    const int kg   = lane >> 4;          // 0..3
    const int wv = blockIdx.x * 4 + (threadIdx.x >> 6);
    const int nw = gridDim.x * 4;
    const int nStrips = (nN + 15) >> 4;

    float4 c0[8], c1[8];

    auto process = [&](float4 (&buf)[8], int ss) {
        // 1) convert current strip fp32 -> bf16 fragments (frees buf regs)
        short8 bf[4];
#pragma unroll
        for (int kk = 0; kk < 4; ++kk) {
            union { unsigned int u[4]; short8 s8; } cv;
            cv.u[0] = cvt2(buf[2 * kk].x,     buf[2 * kk].y);
            cv.u[1] = cvt2(buf[2 * kk].z,     buf[2 * kk].w);
            cv.u[2] = cvt2(buf[2 * kk + 1].x, buf[2 * kk + 1].y);
            cv.u[3] = cvt2(buf[2 * kk + 1].z, buf[2 * kk + 1].w);
            bf[kk] = cv.s8;
        }
        // 2) prefetch strip ss+2*nw into the SAME buffer; pin issue point
        int sp = ss + 2 * nw;
        if (sp < nStrips) load_strip(buf, z, sp, nN, l15, kg);
        __builtin_amdgcn_sched_barrier(0);

        // 3) two halves of 4 ct-tiles each (acc = 16 VGPRs)
        int row = ss * 16 + l15;
        unsigned short* op = outp + (size_t)row * DFEAT + kg * 4;
#pragma unroll
        for (int h = 0; h < 2; ++h) {
            f32x4 acc[4];
#pragma unroll
            for (int ci = 0; ci < 4; ++ci)
                acc[ci] = *(const f32x4*)&bias_lds[(h * 4 + ci) * 16 + kg * 4];
#pragma unroll
            for (int kk = 0; kk < 4; ++kk) {
#pragma unroll
                for (int ci = 0; ci < 4; ++ci) {
                    short8 a = *(const short8*)&Wt[(h * 4 + ci) * 16 + l15][kk * 32 + kg * 8];
                    acc[ci] = __builtin_amdgcn_mfma_f32_16x16x32_bf16(a, bf[kk], acc[ci], 0, 0, 0);
                }
            }
            if (row < nN) {
#pragma unroll
                for (int ci = 0; ci < 4; ++ci) {
                    u32x2 v;
                    v[0] = cvt2(acc[ci][0], acc[ci][1]);
                    v[1] = cvt2(acc[ci][2], acc[ci][3]);
                    *(u32x2*)(op + (h * 4 + ci) * 16) = v;
                }
            }
        }
    };

    int s = wv;
    if (s < nStrips)      load_strip(c0, z, s, nN, l15, kg);
    if (s + nw < nStrips) load_strip(c1, z, s + nw, nN, l15, kg);

    while (s < nStrips) {
        process(c0, s);
        s += nw;
        if (s >= nStrips) break;
        process(c1, s);
        s += nw;
    }
}

// Phase 2: 16 lanes/edge, 8 edges (one "chunk") per wave-iter; 2-deep chunk
// pipeline: idx for chunk n+2 loads before compute of n; gathers for n+2
// reissue right after (idx latency covered by compute n).
__global__ __launch_bounds__(256) void edge_kernel(
    const unsigned short* __restrict__ A, const unsigned short* __restrict__ B,
    const int* __restrict__ src, const int* __restrict__ dst,
    const float* __restrict__ W3, const float* __restrict__ b3,
    float* __restrict__ out, int nE)
{
    const int lane = threadIdx.x & 63;
    const int sub  = lane & 15;
    const int grp  = lane >> 4;

    float w3v[8];
#pragma unroll
    for (int j = 0; j < 8; ++j) w3v[j] = W3[sub * 8 + j];
    const float bb = b3[0];

    const int wv = blockIdx.x * 4 + (threadIdx.x >> 6);
    const int nw = gridDim.x * 4;
    const int nChunk = (nE + 7) >> 3;
    const int nm1 = nE - 1;

    int c = wv;
    if (c >= nChunk) return;

    auto compute = [&](u32x4 av0, u32x4 bv0, u32x4 av1, u32x4 bv1, int cc) {
        float p0 = 0.f, p1 = 0.f;
#pragma unroll
        for (int w = 0; w < 4; ++w) {
            float x0 = fmaxf(bf2f(av0[w] & 0xFFFFu) + bf2f(bv0[w] & 0xFFFFu), 0.f);
            float x1 = fmaxf(bf2f(av0[w] >> 16)     + bf2f(bv0[w] >> 16),     0.f);
            p0 = fmaf(x0, w3v[w * 2], p0);
            p0 = fmaf(x1, w3v[w * 2 + 1], p0);
            float y0 = fmaxf(bf2f(av1[w] & 0xFFFFu) + bf2f(bv1[w] & 0xFFFFu), 0.f);
            float y1 = fmaxf(bf2f(av1[w] >> 16)     + bf2f(bv1[w] >> 16),     0.f);
            p1 = fmaf(y0, w3v[w * 2], p1);
            p1 = fmaf(y1, w3v[w * 2 + 1], p1);
        }
#pragma unroll
        for (int off = 8; off > 0; off >>= 1) {
            p0 += __shfl_xor(p0, off, 64);
            p1 += __shfl_xor(p1, off, 64);
        }
        if (sub == 0) {
            int e0 = cc * 8 + grp, e1 = e0 + 4;
            if (e0 < nE) out[e0] = 1.f / (1.f + __expf(-(p0 + bb)));
            if (e1 < nE) out[e1] = 1.f / (1.f + __expf(-(p1 + bb)));
        }
    };

    // ---- prologue: chunk c -> buffer A, chunk c+nw -> buffer B ----
    int e0 = c * 8 + grp, e1 = e0 + 4;
    int i0 = e0 < nE ? e0 : nm1, i1 = e1 < nE ? e1 : nm1;
    int sA0 = src[i0], dA0 = dst[i0], sA1 = src[i1], dA1 = dst[i1];
    u32x4 avA0 = *(const u32x4*)(A + (size_t)sA0 * DFEAT + sub * 8);
    u32x4 bvA0 = *(const u32x4*)(B + (size_t)dA0 * DFEAT + sub * 8);
    u32x4 avA1 = *(const u32x4*)(A + (size_t)sA1 * DFEAT + sub * 8);
    u32x4 bvA1 = *(const u32x4*)(B + (size_t)dA1 * DFEAT + sub * 8);

    int cB = c + nw; if (cB >= nChunk) cB = nChunk - 1;
    e0 = cB * 8 + grp; e1 = e0 + 4;
    i0 = e0 < nE ? e0 : nm1; i1 = e1 < nE ? e1 : nm1;
    int sB0 = src[i0], dB0 = dst[i0], sB1 = src[i1], dB1 = dst[i1];
    u32x4 avB0 = *(const u32x4*)(A + (size_t)sB0 * DFEAT + sub * 8);
    u32x4 bvB0 = *(const u32x4*)(B + (size_t)dB0 * DFEAT + sub * 8);
    u32x4 avB1 = *(const u32x4*)(A + (size_t)sB1 * DFEAT + sub * 8);
    u32x4 bvB1 = *(const u32x4*)(B + (size_t)dB1 * DFEAT + sub * 8);

    while (true) {
        // ---- buffer A holds chunk c ----
        int cp = c + 2 * nw; if (cp >= nChunk) cp = nChunk - 1;
        e0 = cp * 8 + grp; e1 = e0 + 4;
        i0 = e0 < nE ? e0 : nm1; i1 = e1 < nE ? e1 : nm1;
        int sp0 = src[i0], dp0 = dst[i0], sp1 = src[i1], dp1 = dst[i1];
        compute(avA0, bvA0, avA1, bvA1, c);
        avA0 = *(const u32x4*)(A + (size_t)sp0 * DFEAT + sub * 8);
        bvA0 = *(const u32x4*)(B + (size_t)dp0 * DFEAT + sub * 8);
        avA1 = *(const u32x4*)(A + (size_t)sp1 * DFEAT + sub * 8);
        bvA1 = *(const u32x4*)(B + (size_t)dp1 * DFEAT + sub * 8);
        __builtin_amdgcn_sched_barrier(0);
        c += nw;
        if (c >= nChunk) break;

        // ---- buffer B holds chunk c ----
        cp = c + 2 * nw; if (cp >= nChunk) cp = nChunk - 1;
        e0 = cp * 8 + grp; e1 = e0 + 4;
        i0 = e0 < nE ? e0 : nm1; i1 = e1 < nE ? e1 : nm1;
        sp0 = src[i0]; dp0 = dst[i0]; sp1 = src[i1]; dp1 = dst[i1];
        compute(avB0, bvB0, avB1, bvB1, c);
        avB0 = *(const u32x4*)(A + (size_t)sp0 * DFEAT + sub * 8);
        bvB0 = *(const u32x4*)(B + (size_t)dp0 * DFEAT + sub * 8);
        avB1 = *(const u32x4*)(A + (size_t)sp1 * DFEAT + sub * 8);
        bvB1 = *(const u32x4*)(B + (size_t)dp1 * DFEAT + sub * 8);
        __builtin_amdgcn_sched_barrier(0);
        c += nw;
        if (c >= nChunk) break;
    }
}

// Fallback (only if d_ws too small): direct per-edge dense compute. Slow, correct.
__global__ __launch_bounds__(256) void fallback_kernel(
    const float* __restrict__ zi, const float* __restrict__ zj,
    const int* __restrict__ src, const int* __restrict__ dst,
    const float* __restrict__ W1, const float* __restrict__ b1,
    const float* __restrict__ W3, const float* __restrict__ b3,
    float* __restrict__ out, int nE)
{
    int e = blockIdx.x * blockDim.x + threadIdx.x;
    if (e >= nE) return;
    const float* a = zi + (size_t)src[e] * DFEAT;
    const float* b = zj + (size_t)dst[e] * DFEAT;
    float logit = b3[0];
    for (int h = 0; h < 128; ++h) {
        float acc = b1[h];
        for (int k = 0; k < 128; ++k) acc = fmaf(a[k], W1[(size_t)k * 128 + h], acc);
        for (int k = 0; k < 128; ++k) acc = fmaf(b[k], W1[(size_t)(128 + k) * 128 + h], acc);
        if (acc > 0.f) logit = fmaf(acc, W3[h], logit);
    }
    out[e] = 1.f / (1.f + __expf(-logit));
}

extern "C" void kernel_launch(void* const* d_in, const int* in_sizes, int n_in,
                              void* d_out, int out_size, void* d_ws, size_t ws_size,
                              hipStream_t stream) {
    const float* zi = (const float*)d_in[0];
    const float* zj = (const float*)d_in[1];
    const int*  src = (const int*)d_in[2];
    const int*  dst = (const int*)d_in[3];
    const float* W1 = (const float*)d_in[4];
    const float* b1 = (const float*)d_in[5];
    const float* W3 = (const float*)d_in[6];
    const float* b3 = (const float*)d_in[7];
    float* out = (float*)d_out;

    int nN = in_sizes[0] / DFEAT;
    int nE = in_sizes[2];
    size_t abytes = (size_t)nN * DFEAT * sizeof(unsigned short);

    if (ws_size >= 2 * abytes) {
        unsigned short* A = (unsigned short*)d_ws;
        unsigned short* B = A + (size_t)nN * DFEAT;
        // 512x2 = 1024 blocks = 4/CU residency; 2-deep pipelined strips
        dim3 g1(512, 2, 1);
        node_gemm<<<g1, 256, 0, stream>>>(zi, zj, W1, b1, A, B, nN);
        // 1875 blocks = 7500 waves -> exactly 10 chunks/wave at 600K edges
        edge_kernel<<<1875, 256, 0, stream>>>(A, B, src, dst, W3, b3, out, nE);
    } else {
        fallback_kernel<<<(nE + 255) / 256, 256, 0, stream>>>(
            zi, zj, src, dst, W1, b1, W3, b3, out, nE);
    }
}

// Round 9
// 79.474 us; speedup vs baseline: 1.0985x; 1.0985x over previous
//
#include <hip/hip_runtime.h>
#include <hip/hip_bf16.h>

typedef __attribute__((ext_vector_type(8))) short short8;
typedef __attribute__((ext_vector_type(4))) float f32x4;
typedef __attribute__((ext_vector_type(4))) unsigned int u32x4;
typedef __attribute__((ext_vector_type(2))) unsigned int u32x2;

#define DFEAT 128
#define LDW 136   // Wt row stride in shorts

__device__ __forceinline__ unsigned short f2bf(float f) {
    unsigned int u = __float_as_uint(f);
    u += 0x7FFFu + ((u >> 16) & 1u);   // round-nearest-even
    return (unsigned short)(u >> 16);
}
// packed f32x2 -> bf16x2, RNE (gfx950 v_cvt_pk_bf16_f32)
__device__ __forceinline__ unsigned int cvt2(float lo, float hi) {
    unsigned int r;
    asm("v_cvt_pk_bf16_f32 %0, %1, %2" : "=v"(r) : "v"(lo), "v"(hi));
    return r;
}
__device__ __forceinline__ float bf2f(unsigned int bits) {
    return __uint_as_float(bits << 16);
}

// Issue 8x dwordx4 strip loads via asm volatile: the compiler CANNOT sink or
// fold these to their use point (rounds 6/7 proved it defeats C++-level
// prefetch). Data valid only after an explicit s_waitcnt vmcnt.
__device__ __forceinline__ void pf_issue(f32x4 (&pf)[8], const float* zr) {
    asm volatile("global_load_dwordx4 %0, %1, off"            : "=&v"(pf[0]) : "v"(zr) : "memory");
    asm volatile("global_load_dwordx4 %0, %1, off offset:16"  : "=&v"(pf[1]) : "v"(zr) : "memory");
    asm volatile("global_load_dwordx4 %0, %1, off offset:128" : "=&v"(pf[2]) : "v"(zr) : "memory");
    asm volatile("global_load_dwordx4 %0, %1, off offset:144" : "=&v"(pf[3]) : "v"(zr) : "memory");
    asm volatile("global_load_dwordx4 %0, %1, off offset:256" : "=&v"(pf[4]) : "v"(zr) : "memory");
    asm volatile("global_load_dwordx4 %0, %1, off offset:272" : "=&v"(pf[5]) : "v"(zr) : "memory");
    asm volatile("global_load_dwordx4 %0, %1, off offset:384" : "=&v"(pf[6]) : "v"(zr) : "memory");
    asm volatile("global_load_dwordx4 %0, %1, off offset:400" : "=&v"(pf[7]) : "v"(zr) : "memory");
}

// Phase 1: A[n][:] = zi[n] @ W1[0:128][:] + b1 (table 0); B analogous (table 1).
// One wave per 16x128 strip; swapped MFMA operands -> packed 8B stores.
// Asm-pinned 1-deep strip prefetch. VMEM accounting per iteration:
//   step 2 issues 8 loads (oldest), epilogue issues 8 stores (younger)
//   -> outstanding at loop bottom = 16; s_waitcnt vmcnt(8) retires exactly
//   the 8 loads without waiting on the stores. (Round-8 bug: used vmcnt(16),
//   a no-op -> read stale prefetch regs.) Store count is always 8 because
//   nN % 16 == 0 here (100000) so the row<nN guard never kills a full wave.
__global__ __launch_bounds__(256) void node_gemm(
    const float* __restrict__ zi, const float* __restrict__ zj,
    const float* __restrict__ W1, const float* __restrict__ b1,
    unsigned short* __restrict__ Aout, unsigned short* __restrict__ Bout,
    int nN)
{
    __shared__ unsigned short Wt[128][LDW];   // Wt[col][k] bf16
    __shared__ float bias_lds[128];
    const int table = blockIdx.y;
    const float* __restrict__ z = table ? zj : zi;
    unsigned short* __restrict__ outp = table ? Bout : Aout;

    for (int idx = threadIdx.x; idx < 128 * 128; idx += 256) {
        int c = idx & 127, k = idx >> 7;
        Wt[c][k] = f2bf(W1[(size_t)(table * 128 + k) * DFEAT + c]);
    }
    if (threadIdx.x < 128) bias_lds[threadIdx.x] = table ? 0.f : b1[threadIdx.x];
    __syncthreads();

    const int lane = threadIdx.x & 63;
    const int l15  = lane & 15;
    const int kg   = lane >> 4;          // 0..3
    const int wv = blockIdx.x * 4 + (threadIdx.x >> 6);
    const int nw = gridDim.x * 4;
    const int nStrips = (nN + 15) >> 4;

    f32x4 pf[8];
    int s = wv;
    if (s < nStrips) {
        int row = s * 16 + l15;
        pf_issue(pf, z + (size_t)(row < nN ? row : nN - 1) * DFEAT + kg * 8);
    }
    asm volatile("s_waitcnt vmcnt(0)" ::: "memory");
    __builtin_amdgcn_sched_barrier(0);

    while (s < nStrips) {
        // 1) convert current strip fp32 -> bf16 fragments (frees pf regs)
        short8 bf[4];
#pragma unroll
        for (int kk = 0; kk < 4; ++kk) {
            union { unsigned int u[4]; short8 s8; } cv;
            cv.u[0] = cvt2(pf[2 * kk][0], pf[2 * kk][1]);
            cv.u[1] = cvt2(pf[2 * kk][2], pf[2 * kk][3]);
            cv.u[2] = cvt2(pf[2 * kk + 1][0], pf[2 * kk + 1][1]);
            cv.u[3] = cvt2(pf[2 * kk + 1][2], pf[2 * kk + 1][3]);
            bf[kk] = cv.s8;
        }
        __builtin_amdgcn_sched_barrier(0);

        // 2) issue next strip's loads (latency hides under MFMA + stores)
        int sp = s + nw;
        if (sp < nStrips) {
            int row = sp * 16 + l15;
            pf_issue(pf, z + (size_t)(row < nN ? row : nN - 1) * DFEAT + kg * 8);
        }
        __builtin_amdgcn_sched_barrier(0);

        // 3) two halves of 4 ct-tiles each (acc = 16 VGPRs)
        int row = s * 16 + l15;
        unsigned short* op = outp + (size_t)row * DFEAT + kg * 4;
#pragma unroll
        for (int h = 0; h < 2; ++h) {
            f32x4 acc[4];
#pragma unroll
            for (int ci = 0; ci < 4; ++ci)
                acc[ci] = *(const f32x4*)&bias_lds[(h * 4 + ci) * 16 + kg * 4];
#pragma unroll
            for (int kk = 0; kk < 4; ++kk) {
#pragma unroll
                for (int ci = 0; ci < 4; ++ci) {
                    short8 a = *(const short8*)&Wt[(h * 4 + ci) * 16 + l15][kk * 32 + kg * 8];
                    acc[ci] = __builtin_amdgcn_mfma_f32_16x16x32_bf16(a, bf[kk], acc[ci], 0, 0, 0);
                }
            }
            if (row < nN) {
#pragma unroll
                for (int ci = 0; ci < 4; ++ci) {
                    u32x2 v;
                    v[0] = cvt2(acc[ci][0], acc[ci][1]);
                    v[1] = cvt2(acc[ci][2], acc[ci][3]);
                    *(u32x2*)(op + (h * 4 + ci) * 16) = v;
                }
            }
        }
        s = sp;
        // retire the 8 prefetch loads (oldest of 16 outstanding)
        asm volatile("s_waitcnt vmcnt(8)" ::: "memory");
        __builtin_amdgcn_sched_barrier(0);
    }
}

// Phase 2 (round-6 verbatim, measured 46us): 16 lanes/edge, 8 edges/wave/iter.
__global__ __launch_bounds__(256) void edge_kernel(
    const unsigned short* __restrict__ A, const unsigned short* __restrict__ B,
    const int* __restrict__ src, const int* __restrict__ dst,
    const float* __restrict__ W3, const float* __restrict__ b3,
    float* __restrict__ out, int nE)
{
    const int lane = threadIdx.x & 63;
    const int sub  = lane & 15;
    const int grp  = lane >> 4;

    float w3v[8];
#pragma unroll
    for (int j = 0; j < 8; ++j) w3v[j] = W3[sub * 8 + j];
    const float bb = b3[0];

    int wv = blockIdx.x * 4 + (threadIdx.x >> 6);
    int nw = gridDim.x * 4;

    for (int base = wv * 8; base < nE; base += nw * 8) {
        int e0 = base + grp;
        int e1 = base + 4 + grp;
        bool v0 = e0 < nE, v1 = e1 < nE;
        int s0 = v0 ? src[e0] : 0, d0 = v0 ? dst[e0] : 0;
        int s1 = v1 ? src[e1] : 0, d1 = v1 ? dst[e1] : 0;

        const u32x4* pa0 = (const u32x4*)(A + (size_t)s0 * DFEAT + sub * 8);
        const u32x4* pb0 = (const u32x4*)(B + (size_t)d0 * DFEAT + sub * 8);
        const u32x4* pa1 = (const u32x4*)(A + (size_t)s1 * DFEAT + sub * 8);
        const u32x4* pb1 = (const u32x4*)(B + (size_t)d1 * DFEAT + sub * 8);
        u32x4 av0 = *pa0, bv0 = *pb0;
        u32x4 av1 = *pa1, bv1 = *pb1;

        float p0 = 0.f, p1 = 0.f;
#pragma unroll
        for (int w = 0; w < 4; ++w) {
            float x0 = fmaxf(bf2f(av0[w] & 0xFFFFu) + bf2f(bv0[w] & 0xFFFFu), 0.f);
            float x1 = fmaxf(bf2f(av0[w] >> 16)     + bf2f(bv0[w] >> 16),     0.f);
            p0 = fmaf(x0, w3v[w * 2], p0);
            p0 = fmaf(x1, w3v[w * 2 + 1], p0);
            float y0 = fmaxf(bf2f(av1[w] & 0xFFFFu) + bf2f(bv1[w] & 0xFFFFu), 0.f);
            float y1 = fmaxf(bf2f(av1[w] >> 16)     + bf2f(bv1[w] >> 16),     0.f);
            p1 = fmaf(y0, w3v[w * 2], p1);
            p1 = fmaf(y1, w3v[w * 2 + 1], p1);
        }
#pragma unroll
        for (int off = 8; off > 0; off >>= 1) {
            p0 += __shfl_xor(p0, off, 64);
            p1 += __shfl_xor(p1, off, 64);
        }
        if (sub == 0) {
            if (v0) out[e0] = 1.f / (1.f + __expf(-(p0 + bb)));
            if (v1) out[e1] = 1.f / (1.f + __expf(-(p1 + bb)));
        }
    }
}

// Fallback (only if d_ws too small): direct per-edge dense compute. Slow, correct.
__global__ __launch_bounds__(256) void fallback_kernel(
    const float* __restrict__ zi, const float* __restrict__ zj,
    const int* __restrict__ src, const int* __restrict__ dst,
    const float* __restrict__ W1, const float* __restrict__ b1,
    const float* __restrict__ W3, const float* __restrict__ b3,
    float* __restrict__ out, int nE)
{
    int e = blockIdx.x * blockDim.x + threadIdx.x;
    if (e >= nE) return;
    const float* a = zi + (size_t)src[e] * DFEAT;
    const float* b = zj + (size_t)dst[e] * DFEAT;
    float logit = b3[0];
    for (int h = 0; h < 128; ++h) {
        float acc = b1[h];
        for (int k = 0; k < 128; ++k) acc = fmaf(a[k], W1[(size_t)k * 128 + h], acc);
        for (int k = 0; k < 128; ++k) acc = fmaf(b[k], W1[(size_t)(128 + k) * 128 + h], acc);
        if (acc > 0.f) logit = fmaf(acc, W3[h], logit);
    }
    out[e] = 1.f / (1.f + __expf(-logit));
}

extern "C" void kernel_launch(void* const* d_in, const int* in_sizes, int n_in,
                              void* d_out, int out_size, void* d_ws, size_t ws_size,
                              hipStream_t stream) {
    const float* zi = (const float*)d_in[0];
    const float* zj = (const float*)d_in[1];
    const int*  src = (const int*)d_in[2];
    const int*  dst = (const int*)d_in[3];
    const float* W1 = (const float*)d_in[4];
    const float* b1 = (const float*)d_in[5];
    const float* W3 = (const float*)d_in[6];
    const float* b3 = (const float*)d_in[7];
    float* out = (float*)d_out;

    int nN = in_sizes[0] / DFEAT;
    int nE = in_sizes[2];
    size_t abytes = (size_t)nN * DFEAT * sizeof(unsigned short);

    if (ws_size >= 2 * abytes) {
        unsigned short* A = (unsigned short*)d_ws;
        unsigned short* B = A + (size_t)nN * DFEAT;
        // 256x2 = 512 blocks (2/CU): W-staging amortized over ~6 strips/wave
        dim3 g1(256, 2, 1);
        node_gemm<<<g1, 256, 0, stream>>>(zi, zj, W1, b1, A, B, nN);
        edge_kernel<<<2048, 256, 0, stream>>>(A, B, src, dst, W3, b3, out, nE);
    } else {
        fallback_kernel<<<(nE + 255) / 256, 256, 0, stream>>>(
            zi, zj, src, dst, W1, b1, W3, b3, out, nE);
    }
}